// Round 13
// baseline (257.273 us; speedup 1.0000x reference)
//
#include <hip/hip_runtime.h>
#include <hip/hip_bf16.h>
#include <math.h>

#define WAVE 64
#define GR 32    // GEMM/classifier tile rows (GR=32 proven: full occupancy)
#define GR2 64   // energy tile rows

typedef __attribute__((ext_vector_type(8))) _Float16 half8;
typedef __attribute__((ext_vector_type(4))) float f32x4;
typedef __attribute__((ext_vector_type(4))) _Float16 half4;

// ---------------- CSR build: count+rank (r28: 8 edges/thread) + W/Wp1/Wl pack fused -----
// r28: 8 independent atomicAdd->rank-store chains per thread (same MLP fix that took
// scatter 43 -> ~13 us in r24); rank stores are coalesced int4.
__global__ void count_pack(const int* __restrict__ dst, int* __restrict__ deg,
                           int* __restrict__ rank, int E, int nbC,
                           const float* __restrict__ W1, const float* __restrict__ W2,
                           _Float16* __restrict__ W1h, _Float16* __restrict__ W2h,
                           const float* __restrict__ Wp1, int HP,
                           _Float16* __restrict__ Ph,
                           const float* __restrict__ Wl, int C,
                           _Float16* __restrict__ Wlh) {
    int b = blockIdx.x;
    if (b < nbC) {
        int e0 = (b * 256 + threadIdx.x) * 8;
        if (e0 + 7 < E) {
            int4 d0 = *(const int4*)(dst + e0);
            int4 d1 = *(const int4*)(dst + e0 + 4);
            int4 r0, r1;
            r0.x = atomicAdd(&deg[d0.x], 1);
            r0.y = atomicAdd(&deg[d0.y], 1);
            r0.z = atomicAdd(&deg[d0.z], 1);
            r0.w = atomicAdd(&deg[d0.w], 1);
            r1.x = atomicAdd(&deg[d1.x], 1);
            r1.y = atomicAdd(&deg[d1.y], 1);
            r1.z = atomicAdd(&deg[d1.z], 1);
            r1.w = atomicAdd(&deg[d1.w], 1);
            *(int4*)(rank + e0) = r0;
            *(int4*)(rank + e0 + 4) = r1;
        } else {
            for (int e = e0; e < E; ++e) rank[e] = atomicAdd(&deg[dst[e]], 1);
        }
    } else if (b < nbC + 128) {
        int pb = b - nbC;   // 0..127: first 64 -> W1, next 64 -> W2
        const float* W = (pb >= 64) ? W2 : W1;
        _Float16* Hf = (pb >= 64) ? W2h : W1h;
        int idx = (pb & 63) * 256 + threadIdx.x;   // 0..16383
        int j = idx & 7;
        int lane = (idx >> 3) & 63;
        int kc = (idx >> 9) & 3;
        int nt = idx >> 11;
        int k = kc * 32 + (lane >> 4) * 8 + j;
        int ncol = nt * 16 + (lane & 15);
        Hf[idx] = (_Float16)W[k * 128 + ncol];
    } else if (b < nbC + 144) {
        int idx = (b - nbC - 128) * 256 + threadIdx.x;   // 0..4095
        int j = idx & 7;
        int lane = (idx >> 3) & 63;
        int kc = (idx >> 9) & 3;
        int nt = idx >> 11;                               // 0..1
        int k = kc * 32 + (lane >> 4) * 8 + j;
        int ncol = nt * 16 + (lane & 15);
        float x = (ncol < HP) ? Wp1[k * HP + ncol] : 0.f;
        Ph[idx] = (_Float16)x;
    } else {
        int idx = (b - nbC - 144) * 256 + threadIdx.x;   // 0..131071
        int j = idx & 7;
        int lane = (idx >> 3) & 63;
        int kc = (idx >> 9) & 3;
        int nt = idx >> 11;                               // 0..63
        int k = kc * 32 + (lane >> 4) * 8 + j;
        int ncol = nt * 16 + (lane & 15);
        float x = (ncol < C) ? Wl[(size_t)k * C + ncol] : 0.f;
        Wlh[idx] = (_Float16)x;
    }
}

__global__ void scan_block(const int* __restrict__ in, int* __restrict__ part,
                           int* __restrict__ bsums, int n) {
    __shared__ int tmp[256];
    int tid = threadIdx.x;
    int i = blockIdx.x * 256 + tid;
    int v = (i < n) ? in[i] : 0;
    tmp[tid] = v;
    __syncthreads();
    for (int o = 1; o < 256; o <<= 1) {
        int t = (tid >= o) ? tmp[tid - o] : 0;
        __syncthreads();
        tmp[tid] += t;
        __syncthreads();
    }
    if (i < n) part[i] = tmp[tid] - v;
    if (tid == 255) bsums[blockIdx.x] = tmp[255];
}

__global__ void scan_finish(const int* __restrict__ part, const int* __restrict__ bsums,
                            int* __restrict__ offs, int n, int Etot) {
    __shared__ int acc[256];
    int b = blockIdx.x, tid = threadIdx.x;
    int s = 0;
    for (int i = tid; i < b; i += 256) s += bsums[i];
    acc[tid] = s;
    __syncthreads();
    for (int o = 128; o > 0; o >>= 1) {
        if (tid < o) acc[tid] += acc[tid + o];
        __syncthreads();
    }
    int prefix = acc[0];
    int i = b * 256 + tid;
    if (i < n) offs[i] = part[i] + prefix;
    if (b == 0 && tid == 0) offs[n] = Etot;
}

// ---------------- device bodies for the merged scatter||gemm dispatch --------------
__device__ __forceinline__ void dev_scatter(int bid,
                                            const int* __restrict__ src,
                                            const int* __restrict__ dst,
                                            const int* __restrict__ rank,
                                            const int* __restrict__ offs,
                                            int* __restrict__ csr_src, int E) {
    int e0 = (bid * 256 + threadIdx.x) * 8;
    if (e0 + 7 < E) {
        int4 d0 = *(const int4*)(dst + e0);
        int4 d1 = *(const int4*)(dst + e0 + 4);
        int4 s0 = *(const int4*)(src + e0);
        int4 s1 = *(const int4*)(src + e0 + 4);
        int4 r0 = *(const int4*)(rank + e0);
        int4 r1 = *(const int4*)(rank + e0 + 4);
        csr_src[offs[d0.x] + r0.x] = s0.x;
        csr_src[offs[d0.y] + r0.y] = s0.y;
        csr_src[offs[d0.z] + r0.z] = s0.z;
        csr_src[offs[d0.w] + r0.w] = s0.w;
        csr_src[offs[d1.x] + r1.x] = s1.x;
        csr_src[offs[d1.y] + r1.y] = s1.y;
        csr_src[offs[d1.z] + r1.z] = s1.z;
        csr_src[offs[d1.w] + r1.w] = s1.w;
    } else {
        for (int e = e0; e < E; ++e) {
            csr_src[offs[dst[e]] + rank[e]] = src[e];
        }
    }
}

__device__ __forceinline__ void dev_gemm_f32(int bid, char* lds,
                                             const float* __restrict__ X,
                                             const _Float16* __restrict__ Bh,
                                             const float* __restrict__ a_s,
                                             const float* __restrict__ a_d,
                                             _Float16* __restrict__ Hout,
                                             float* __restrict__ as_,
                                             float* __restrict__ ad_, int n) {
    _Float16* Xh = (_Float16*)lds;
    float* Hs = (float*)lds;

    int tid = threadIdx.x;
    int base = bid * GR;
    const float4* X4 = (const float4*)X;

#pragma unroll
    for (int i = 0; i < 4; ++i) {
        int idx = i * 256 + tid;
        int row = idx >> 5, c4 = idx & 31;
        int rs = base + row; if (rs >= n) rs = n - 1;
        float4 v = X4[(size_t)rs * 32 + c4];
        half4 hv = {(_Float16)v.x, (_Float16)v.y, (_Float16)v.z, (_Float16)v.w};
        *(half4*)(Xh + row * 136 + c4 * 4) = hv;
    }
    __syncthreads();

    int wid = tid >> 6, lane = tid & 63;
    int quad = lane >> 4, l16 = lane & 15;
    int rowA = (wid & 1) * 16 + l16;
    int ntb = (wid >> 1) * 4;

    f32x4 acc[4];
#pragma unroll
    for (int t = 0; t < 4; ++t) acc[t] = (f32x4){0.f, 0.f, 0.f, 0.f};

    for (int kc = 0; kc < 4; ++kc) {
        half8 Ah = *(const half8*)(Xh + rowA * 136 + kc * 32 + quad * 8);
#pragma unroll
        for (int nt = 0; nt < 4; ++nt) {
            half8 Bv = *(const half8*)(Bh + (((size_t)((ntb + nt) * 4 + kc)) * 64 + lane) * 8);
            acc[nt] = __builtin_amdgcn_mfma_f32_16x16x32_f16(Ah, Bv, acc[nt], 0, 0, 0);
        }
    }
    __syncthreads();

    int rowD0 = (wid & 1) * 16 + quad * 4;
#pragma unroll
    for (int nt = 0; nt < 4; ++nt)
#pragma unroll
        for (int r = 0; r < 4; ++r)
            Hs[(rowD0 + r) * 136 + (ntb + nt) * 16 + l16] = acc[nt][r];
    __syncthreads();

    const float4* Hs4 = (const float4*)Hs;
    half4* H4 = (half4*)Hout;
#pragma unroll
    for (int i = 0; i < 4; ++i) {
        int idx = i * 256 + tid;
        int row = idx >> 5, c4 = idx & 31;
        int grow = base + row;
        if (grow < n) {
            float4 v = Hs4[row * 34 + c4];
            half4 hv = {(_Float16)v.x, (_Float16)v.y, (_Float16)v.z, (_Float16)v.w};
            H4[(size_t)grow * 32 + c4] = hv;
        }
    }

    // dots (fp32 from LDS): thread -> row tid>>3, eighth tid&7, reduce over 8 lanes
    int drow = tid >> 3, q = tid & 7;
    const float4* as4 = (const float4*)a_s;
    const float4* ad4 = (const float4*)a_d;
    float s = 0.f, d = 0.f;
#pragma unroll
    for (int j = 0; j < 4; ++j) {
        float4 v = Hs4[drow * 34 + q * 4 + j];
        float4 a = as4[q * 4 + j];
        float4 b = ad4[q * 4 + j];
        s += v.x * a.x + v.y * a.y + v.z * a.z + v.w * a.w;
        d += v.x * b.x + v.y * b.y + v.z * b.z + v.w * b.w;
    }
    s += __shfl_xor(s, 1, WAVE); s += __shfl_xor(s, 2, WAVE); s += __shfl_xor(s, 4, WAVE);
    d += __shfl_xor(d, 1, WAVE); d += __shfl_xor(d, 2, WAVE); d += __shfl_xor(d, 4, WAVE);
    if (q == 0 && base + drow < n) {
        as_[base + drow] = s;
        ad_[base + drow] = d;
    }
}

// merged dispatch — blocks [0,nbS): atomic-free scatter; [nbS,nbS+nbT): GEMM L1.
__global__ __launch_bounds__(256) void scatter_gemm(const int* __restrict__ src,
                                                    const int* __restrict__ dst,
                                                    const int* __restrict__ rank,
                                                    const int* __restrict__ offs,
                                                    int* __restrict__ csr_src, int E, int nbS,
                                                    const float* __restrict__ X,
                                                    const _Float16* __restrict__ Bh,
                                                    const float* __restrict__ a_s,
                                                    const float* __restrict__ a_d,
                                                    _Float16* __restrict__ Hout,
                                                    float* __restrict__ as_,
                                                    float* __restrict__ ad_, int n) {
    __shared__ char lds[GR * 136 * 4];
    if (blockIdx.x < nbS) {
        dev_scatter(blockIdx.x, src, dst, rank, offs, csr_src, E);
    } else {
        dev_gemm_f32(blockIdx.x - nbS, lds, X, Bh, a_s, a_d, Hout, as_, ad_, n);
    }
}

// ---------------- same GEMM with fp16 X input (layer-2) — staging is pure copy -----
__global__ __launch_bounds__(256) void gemm_mfma_h(const _Float16* __restrict__ X,
                                                   const _Float16* __restrict__ Bh,
                                                   const float* __restrict__ a_s,
                                                   const float* __restrict__ a_d,
                                                   _Float16* __restrict__ Hout,
                                                   float* __restrict__ as_,
                                                   float* __restrict__ ad_, int n) {
    __shared__ char lds[GR * 136 * 4];
    _Float16* Xh = (_Float16*)lds;
    float* Hs = (float*)lds;

    int tid = threadIdx.x;
    int base = blockIdx.x * GR;
    const half8* X8 = (const half8*)X;

#pragma unroll
    for (int i = 0; i < 2; ++i) {
        int idx = i * 256 + tid;            // 0..511: 32 rows x 16 half8
        int row = idx >> 4, c8 = idx & 15;
        int rs = base + row; if (rs >= n) rs = n - 1;
        *(half8*)(Xh + row * 136 + c8 * 8) = X8[(size_t)rs * 16 + c8];
    }
    __syncthreads();

    int wid = tid >> 6, lane = tid & 63;
    int quad = lane >> 4, l16 = lane & 15;
    int rowA = (wid & 1) * 16 + l16;
    int ntb = (wid >> 1) * 4;

    f32x4 acc[4];
#pragma unroll
    for (int t = 0; t < 4; ++t) acc[t] = (f32x4){0.f, 0.f, 0.f, 0.f};

    for (int kc = 0; kc < 4; ++kc) {
        half8 Ah = *(const half8*)(Xh + rowA * 136 + kc * 32 + quad * 8);
#pragma unroll
        for (int nt = 0; nt < 4; ++nt) {
            half8 Bv = *(const half8*)(Bh + (((size_t)((ntb + nt) * 4 + kc)) * 64 + lane) * 8);
            acc[nt] = __builtin_amdgcn_mfma_f32_16x16x32_f16(Ah, Bv, acc[nt], 0, 0, 0);
        }
    }
    __syncthreads();

    int rowD0 = (wid & 1) * 16 + quad * 4;
#pragma unroll
    for (int nt = 0; nt < 4; ++nt)
#pragma unroll
        for (int r = 0; r < 4; ++r)
            Hs[(rowD0 + r) * 136 + (ntb + nt) * 16 + l16] = acc[nt][r];
    __syncthreads();

    const float4* Hs4 = (const float4*)Hs;
    half4* H4 = (half4*)Hout;
#pragma unroll
    for (int i = 0; i < 4; ++i) {
        int idx = i * 256 + tid;
        int row = idx >> 5, c4 = idx & 31;
        int grow = base + row;
        if (grow < n) {
            float4 v = Hs4[row * 34 + c4];
            half4 hv = {(_Float16)v.x, (_Float16)v.y, (_Float16)v.z, (_Float16)v.w};
            H4[(size_t)grow * 32 + c4] = hv;
        }
    }

    int drow = tid >> 3, q = tid & 7;
    const float4* as4 = (const float4*)a_s;
    const float4* ad4 = (const float4*)a_d;
    float s = 0.f, d = 0.f;
#pragma unroll
    for (int j = 0; j < 4; ++j) {
        float4 v = Hs4[drow * 34 + q * 4 + j];
        float4 a = as4[q * 4 + j];
        float4 b = ad4[q * 4 + j];
        s += v.x * a.x + v.y * a.y + v.z * a.z + v.w * a.w;
        d += v.x * b.x + v.y * b.y + v.z * b.z + v.w * b.w;
    }
    s += __shfl_xor(s, 1, WAVE); s += __shfl_xor(s, 2, WAVE); s += __shfl_xor(s, 4, WAVE);
    d += __shfl_xor(d, 1, WAVE); d += __shfl_xor(d, 2, WAVE); d += __shfl_xor(d, 4, WAVE);
    if (q == 0 && base + drow < n) {
        as_[base + drow] = s;
        ad_[base + drow] = d;
    }
}

__device__ __forceinline__ float leaky02(float x) { return x > 0.f ? x : 0.2f * x; }

// ---------------- GAT aggregation: fused edge weights, 8 edges/iter, dual acc -----------
__global__ __launch_bounds__(256) void gat_aggregate(const _Float16* __restrict__ h,
                                                     const int* __restrict__ csr_src,
                                                     const float* __restrict__ as_,
                                                     const float* __restrict__ ad_,
                                                     const int* __restrict__ offs,
                                                     const float* __restrict__ bias,
                                                     _Float16* __restrict__ out, int n, int act) {
    int node = blockIdx.x * 4 + (threadIdx.x >> 6);
    int lane = threadIdx.x & 63;
    if (node >= n) return;
    int beg = offs[node], end = offs[node + 1];
    int q4 = lane >> 4, l = lane & 15;
    const half8* h8 = (const half8*)h;

    float adn = ad_[node];
    float w_self = __expf(leaky02(as_[node] + adn));
    float facc[8], facc2[8];
    {
        half8 v = h8[(size_t)node * 16 + l];
        float ws = (q4 == 0) ? w_self : 0.f;
#pragma unroll
        for (int i = 0; i < 8; ++i) { facc[i] = ws * (float)v[i]; facc2[i] = 0.f; }
    }
    float sacc = (lane == 0) ? w_self : 0.f;
    for (int j = beg; j < end; j += 8) {
        int j0 = j + q4;
        int j1 = j0 + 4;
        bool vA = j0 < end;
        bool vB = j1 < end;
        int jA = vA ? j0 : (end - 1);
        int jB = vB ? j1 : (end - 1);
        int sA = csr_src[jA];
        int sB = csr_src[jB];
        half8 a = h8[(size_t)sA * 16 + l];
        half8 b = h8[(size_t)sB * 16 + l];
        float asA = as_[sA];
        float asB = as_[sB];
        float wA = vA ? __expf(leaky02(asA + adn)) : 0.f;
        float wB = vB ? __expf(leaky02(asB + adn)) : 0.f;
#pragma unroll
        for (int i = 0; i < 8; ++i) {
            facc[i]  = fmaf(wA, (float)a[i], facc[i]);
            facc2[i] = fmaf(wB, (float)b[i], facc2[i]);
        }
        sacc += (l == 0) ? (wA + wB) : 0.f;
    }
#pragma unroll
    for (int i = 0; i < 8; ++i) {
        facc[i] += facc2[i];
        facc[i] += __shfl_xor(facc[i], 16, WAVE);
        facc[i] += __shfl_xor(facc[i], 32, WAVE);
    }
    sacc += __shfl_xor(sacc, 16, WAVE);
    sacc += __shfl_xor(sacc, 32, WAVE);
    float inv_s = 1.f / __shfl(sacc, 0, WAVE);
    if (q4 == 0) {
        const float4* b4 = (const float4*)bias;
        float4 b0 = b4[l * 2], b1 = b4[l * 2 + 1];
        float o[8];
        o[0] = fmaf(facc[0], inv_s, b0.x);
        o[1] = fmaf(facc[1], inv_s, b0.y);
        o[2] = fmaf(facc[2], inv_s, b0.z);
        o[3] = fmaf(facc[3], inv_s, b0.w);
        o[4] = fmaf(facc[4], inv_s, b1.x);
        o[5] = fmaf(facc[5], inv_s, b1.y);
        o[6] = fmaf(facc[6], inv_s, b1.z);
        o[7] = fmaf(facc[7], inv_s, b1.w);
        if (act == 1) {
#pragma unroll
            for (int i = 0; i < 8; ++i) o[i] = o[i] > 0.f ? o[i] : expm1f(o[i]);
        }
        half8 hv;
#pragma unroll
        for (int i = 0; i < 8; ++i) hv[i] = (_Float16)o[i];
        ((half8*)(out + (size_t)node * 128))[l] = hv;
    }
}

// ---------------- energy via fp16 MFMA; GR2=64 rows, all 4 waves active ------------
__global__ __launch_bounds__(256) void energy_mfma(const _Float16* __restrict__ X,
                                                   const _Float16* __restrict__ Ph,
                                                   const float* __restrict__ bp1,
                                                   const float* __restrict__ Wp2,
                                                   const float* __restrict__ bp2,
                                                   float* __restrict__ energy, int n, int HP) {
    __shared__ _Float16 Xh[GR2 * 136];   // 17408 B
    int tid = threadIdx.x;
    int base = blockIdx.x * GR2;
    const half8* X8 = (const half8*)X;
#pragma unroll
    for (int i = 0; i < 4; ++i) {
        int idx = i * 256 + tid;            // 64 rows x 16 half8
        int row = idx >> 4, c8 = idx & 15;
        int rs = base + row; if (rs >= n) rs = n - 1;
        *(half8*)(Xh + row * 136 + c8 * 8) = X8[(size_t)rs * 16 + c8];
    }
    __syncthreads();

    int wid = tid >> 6, lane = tid & 63;
    int quad = lane >> 4, l16 = lane & 15;
    int rowA = wid * 16 + l16;

    f32x4 acc0 = (f32x4){0.f, 0.f, 0.f, 0.f};
    f32x4 acc1 = (f32x4){0.f, 0.f, 0.f, 0.f};
    for (int kc = 0; kc < 4; ++kc) {
        half8 Ah = *(const half8*)(Xh + rowA * 136 + kc * 32 + quad * 8);
        half8 B0 = *(const half8*)(Ph + (((size_t)kc) * 64 + lane) * 8);
        half8 B1 = *(const half8*)(Ph + (((size_t)(4 + kc)) * 64 + lane) * 8);
        acc0 = __builtin_amdgcn_mfma_f32_16x16x32_f16(Ah, B0, acc0, 0, 0, 0);
        acc1 = __builtin_amdgcn_mfma_f32_16x16x32_f16(Ah, B1, acc1, 0, 0, 0);
    }

    float b0 = bp1[l16];
    float w0 = Wp2[l16];
    int c1 = 16 + l16;
    int c1c = c1 < HP ? c1 : HP - 1;
    float b1 = bp1[c1c];
    float w1 = (c1 < HP) ? Wp2[c1c] : 0.f;
    float bp2v = bp2[0];
#pragma unroll
    for (int r = 0; r < 4; ++r) {
        float h0 = acc0[r] + b0;
        h0 = h0 > 0.f ? h0 : 0.f;
        float h1 = acc1[r] + b1;
        h1 = h1 > 0.f ? h1 : 0.f;
        float v = h0 * w0 + h1 * w1;
        v += __shfl_xor(v, 1, WAVE);
        v += __shfl_xor(v, 2, WAVE);
        v += __shfl_xor(v, 4, WAVE);
        v += __shfl_xor(v, 8, WAVE);
        int row = base + wid * 16 + quad * 4 + r;
        if (l16 == 0 && row < n) energy[row] = v + bp2v;
    }
}

// ---------------- r28: segment softmax-pool, 2 passes (max; fused sum+accumulate) -------
// Unnormalized accumulate acc += exp(e-m)*x alongside partial s; both reduced through
// the same LDS tree; scale by 1/s once at the end.
__global__ __launch_bounds__(256) void seg_pool(const _Float16* __restrict__ X,
                                                const float* __restrict__ energy,
                                                const int* __restrict__ node_pos,
                                                float* __restrict__ pooled) {
    int g = blockIdx.x >> 1;
    int bn = blockIdx.x & 1;          // which 64-col half
    int beg = node_pos[g], end = node_pos[g + 1];
    int tid = threadIdx.x;
    int wid = tid >> 6, lane = tid & 63;
    __shared__ float swr[4];
    __shared__ float4 red[256];
    __shared__ float ssum[256];

    float m = -INFINITY;
    for (int i = beg + tid; i < end; i += 256) m = fmaxf(m, energy[i]);
#pragma unroll
    for (int o = 1; o < 64; o <<= 1) m = fmaxf(m, __shfl_xor(m, o, WAVE));
    if (lane == 0) swr[wid] = m;
    __syncthreads();
    m = fmaxf(fmaxf(swr[0], swr[1]), fmaxf(swr[2], swr[3]));

    int cq = tid & 15;       // 4 cols each -> 64 cols per block
    int rg = tid >> 4;       // 16 row-groups
    const half4* X4 = (const half4*)X;   // 32 half4 per row
    float4 acc = make_float4(0.f, 0.f, 0.f, 0.f);
    float s = 0.f;
#pragma unroll 2
    for (int i = beg + rg; i < end; i += 16) {
        float w = __expf(energy[i] - m);
        half4 v = X4[(size_t)i * 32 + bn * 16 + cq];
        s += w;
        acc.x = fmaf(w, (float)v.x, acc.x);
        acc.y = fmaf(w, (float)v.y, acc.y);
        acc.z = fmaf(w, (float)v.z, acc.z);
        acc.w = fmaf(w, (float)v.w, acc.w);
    }
    red[tid] = acc;
    ssum[tid] = s;
#pragma unroll
    for (int o = 8; o >= 1; o >>= 1) {
        __syncthreads();
        if (rg < o) {
            float4 t = red[tid + o * 16];
            acc.x += t.x; acc.y += t.y; acc.z += t.z; acc.w += t.w;
            red[tid] = acc;
            s += ssum[tid + o * 16];
            ssum[tid] = s;
        }
    }
    if (rg == 0) {
        float inv = (end > beg && s > 0.f) ? 1.f / s : 0.f;
        float4 o;
        o.x = acc.x * inv; o.y = acc.y * inv; o.z = acc.z * inv; o.w = acc.w * inv;
        ((float4*)(pooled + (size_t)g * 128 + bn * 64))[cq] = o;
    }
}

// ---------------- classifier GEMM pooled[G x 128] @ Wl[128 x C] via fp16 MFMA ------
__global__ __launch_bounds__(256) void classify_mfma(const float* __restrict__ P,
                                                     const _Float16* __restrict__ Wlh,
                                                     const float* __restrict__ bl,
                                                     float* __restrict__ out,
                                                     int G_, int C, int nbM) {
    __shared__ _Float16 Xh[GR * 136];
    int tid = threadIdx.x;
    int bm = blockIdx.x % nbM;
    int bn = blockIdx.x / nbM;
    int base = bm * GR;
    const float4* X4 = (const float4*)P;
#pragma unroll
    for (int i = 0; i < 4; ++i) {
        int idx = i * 256 + tid;
        int row = idx >> 5, c4 = idx & 31;
        int rs = base + row; if (rs >= G_) rs = G_ - 1;
        float4 v = X4[(size_t)rs * 32 + c4];
        half4 hv = {(_Float16)v.x, (_Float16)v.y, (_Float16)v.z, (_Float16)v.w};
        *(half4*)(Xh + row * 136 + c4 * 4) = hv;
    }
    __syncthreads();

    int wid = tid >> 6, lane = tid & 63;
    int quad = lane >> 4, l16 = lane & 15;
    int rowA = (wid & 1) * 16 + l16;
    int ntb = bn * 8 + (wid >> 1) * 4;   // global 16-col tile index

    f32x4 acc[4];
#pragma unroll
    for (int t = 0; t < 4; ++t) acc[t] = (f32x4){0.f, 0.f, 0.f, 0.f};

    for (int kc = 0; kc < 4; ++kc) {
        half8 Ah = *(const half8*)(Xh + rowA * 136 + kc * 32 + quad * 8);
#pragma unroll
        for (int nt = 0; nt < 4; ++nt) {
            half8 Bv = *(const half8*)(Wlh + (((size_t)((ntb + nt) * 4 + kc)) * 64 + lane) * 8);
            acc[nt] = __builtin_amdgcn_mfma_f32_16x16x32_f16(Ah, Bv, acc[nt], 0, 0, 0);
        }
    }

    int row0 = base + (wid & 1) * 16 + quad * 4;
#pragma unroll
    for (int nt = 0; nt < 4; ++nt) {
        int col = (ntb + nt) * 16 + l16;
        if (col < C) {
            float b = bl[col];
#pragma unroll
            for (int r = 0; r < 4; ++r) {
                int row = row0 + r;
                if (row < G_) out[(size_t)row * C + col] = acc[nt][r] + b;
            }
        }
    }
}

extern "C" void kernel_launch(void* const* d_in, const int* in_sizes, int n_in,
                              void* d_out, int out_size, void* d_ws, size_t ws_size,
                              hipStream_t stream) {
    const float* cfg_nodes = (const float*)d_in[0];
    const int* rel = (const int*)d_in[1];
    const int* node_pos = (const int*)d_in[2];
    const float* W_g1 = (const float*)d_in[3];
    const float* att_src1 = (const float*)d_in[4];
    const float* att_dst1 = (const float*)d_in[5];
    const float* b_g1 = (const float*)d_in[6];
    const float* W_g2 = (const float*)d_in[7];
    const float* att_src2 = (const float*)d_in[8];
    const float* att_dst2 = (const float*)d_in[9];
    const float* b_g2 = (const float*)d_in[10];
    const float* Wp1 = (const float*)d_in[11];
    const float* bp1 = (const float*)d_in[12];
    const float* Wp2 = (const float*)d_in[13];
    const float* bp2 = (const float*)d_in[14];
    const float* Wl = (const float*)d_in[15];
    const float* bl = (const float*)d_in[16];

    const int N = in_sizes[0] / 128;
    const int E = in_sizes[1] / 2;
    const int G = in_sizes[2] - 1;
    const int HP = in_sizes[12];
    const int C = out_size / G;

    const int* srcArr = rel;
    const int* dstArr = rel + E;

    char* w = (char*)d_ws;
    auto carve = [&](size_t bytes) -> char* {
        char* p = w;
        w += (bytes + 255) & ~(size_t)255;
        return p;
    };
    _Float16* bufH = (_Float16*)carve((size_t)N * 128 * 2);   // gemm output (gat gather src)
    _Float16* bufF = (_Float16*)carve((size_t)N * 128 * 2);   // aggregate output (fp16)
    float* asv = (float*)carve((size_t)N * 4);
    float* adv = (float*)carve((size_t)N * 4);
    float* energy = (float*)carve((size_t)N * 4);
    int* deg = (int*)carve((size_t)N * 4);
    int* offs = (int*)carve((size_t)(N + 1) * 4);
    int* csr_src = (int*)carve((size_t)E * 4);
    int* rank = (int*)carve((size_t)E * 4);
    int* bsums = (int*)carve(1024);
    _Float16* W1h = (_Float16*)carve(16384 * 2);
    _Float16* W2h = (_Float16*)carve(16384 * 2);
    _Float16* Ph = (_Float16*)carve(4096 * 2);
    _Float16* Wlh = (_Float16*)carve(131072 * 2);
    float* pooled = (float*)carve((size_t)G * 128 * 4);

    const int nbN = (N + 255) / 256;
    const int nbC = ((E + 7) / 8 + 255) / 256;   // count: 8 edges/thread (r28)
    const int nbS = ((E + 7) / 8 + 255) / 256;   // scatter: 8 edges/thread
    const int nbT = (N + GR - 1) / GR;           // GEMM tiles (32 rows)
    const int nbT2 = (N + GR2 - 1) / GR2;        // energy tiles (64 rows)
    const int nbM = (G + GR - 1) / GR;           // classifier row tiles
    const int nbCt = (C + 127) / 128;            // classifier col slabs

    // ---- CSR build (rank-based) + all weight packs ----
    hipMemsetAsync(deg, 0, (size_t)N * 4, stream);
    count_pack<<<nbC + 656, 256, 0, stream>>>(dstArr, deg, rank, E, nbC,
                                              W_g1, W_g2, W1h, W2h, Wp1, HP, Ph,
                                              Wl, C, Wlh);
    scan_block<<<nbN, 256, 0, stream>>>(deg, offs, bsums, N);
    scan_finish<<<nbN, 256, 0, stream>>>(offs, bsums, offs, N, E);

    // ---- merged: atomic-free scatter || GAT layer-1 GEMM (independent work) ----
    scatter_gemm<<<nbS + nbT, 256, 0, stream>>>(srcArr, dstArr, rank, offs, csr_src, E, nbS,
                                                cfg_nodes, W1h, att_src1, att_dst1,
                                                bufH, asv, adv, N);

    // ---- GAT layer 1 aggregate ----
    gat_aggregate<<<(N + 3) / 4, 256, 0, stream>>>(bufH, csr_src, asv, adv, offs, b_g1, bufF, N, 1);

    // ---- GAT layer 2 (fp16 input) ----
    gemm_mfma_h<<<nbT, 256, 0, stream>>>(bufF, W2h, att_src2, att_dst2,
                                         bufH, asv, adv, N);
    gat_aggregate<<<(N + 3) / 4, 256, 0, stream>>>(bufH, csr_src, asv, adv, offs, b_g2, bufF, N, 0);

    // ---- energy (fp16 MFMA, GR2=64) + pooling + classifier ----
    energy_mfma<<<nbT2, 256, 0, stream>>>(bufF, Ph, bp1, Wp2, bp2, energy, N, HP);
    seg_pool<<<G * 2, 256, 0, stream>>>(bufF, energy, node_pos, pooled);
    classify_mfma<<<nbM * nbCt, 256, 0, stream>>>(pooled, Wlh, bl, (float*)d_out, G, C, nbM);
}

// Round 14
// 254.572 us; speedup vs baseline: 1.0106x; 1.0106x over previous
//
#include <hip/hip_runtime.h>
#include <hip/hip_bf16.h>
#include <math.h>

#define WAVE 64
#define GR 32    // GEMM/classifier tile rows (GR=32 proven: full occupancy)
#define GR2 64   // energy tile rows

typedef __attribute__((ext_vector_type(8))) _Float16 half8;
typedef __attribute__((ext_vector_type(4))) float f32x4;
typedef __attribute__((ext_vector_type(4))) _Float16 half4;

// ---------------- CSR build: count+rank (2 edges/thread, r27-proven) + W packs ----------
__global__ void count_pack(const int* __restrict__ dst, int* __restrict__ deg,
                           int* __restrict__ rank, int E, int nbC,
                           const float* __restrict__ W1, const float* __restrict__ W2,
                           _Float16* __restrict__ W1h, _Float16* __restrict__ W2h,
                           const float* __restrict__ Wp1, int HP,
                           _Float16* __restrict__ Ph,
                           const float* __restrict__ Wl, int C,
                           _Float16* __restrict__ Wlh) {
    int b = blockIdx.x;
    if (b < nbC) {
        int e = (b * 256 + threadIdx.x) * 2;
        if (e + 1 < E) {
            int2 d = *(const int2*)(dst + e);
            int r0 = atomicAdd(&deg[d.x], 1);
            int r1 = atomicAdd(&deg[d.y], 1);
            *(int2*)(rank + e) = make_int2(r0, r1);
        } else if (e < E) {
            rank[e] = atomicAdd(&deg[dst[e]], 1);
        }
    } else if (b < nbC + 128) {
        int pb = b - nbC;   // 0..127: first 64 -> W1, next 64 -> W2
        const float* W = (pb >= 64) ? W2 : W1;
        _Float16* Hf = (pb >= 64) ? W2h : W1h;
        int idx = (pb & 63) * 256 + threadIdx.x;   // 0..16383
        int j = idx & 7;
        int lane = (idx >> 3) & 63;
        int kc = (idx >> 9) & 3;
        int nt = idx >> 11;
        int k = kc * 32 + (lane >> 4) * 8 + j;
        int ncol = nt * 16 + (lane & 15);
        Hf[idx] = (_Float16)W[k * 128 + ncol];
    } else if (b < nbC + 144) {
        int idx = (b - nbC - 128) * 256 + threadIdx.x;   // 0..4095
        int j = idx & 7;
        int lane = (idx >> 3) & 63;
        int kc = (idx >> 9) & 3;
        int nt = idx >> 11;                               // 0..1
        int k = kc * 32 + (lane >> 4) * 8 + j;
        int ncol = nt * 16 + (lane & 15);
        float x = (ncol < HP) ? Wp1[k * HP + ncol] : 0.f;
        Ph[idx] = (_Float16)x;
    } else {
        int idx = (b - nbC - 144) * 256 + threadIdx.x;   // 0..131071
        int j = idx & 7;
        int lane = (idx >> 3) & 63;
        int kc = (idx >> 9) & 3;
        int nt = idx >> 11;                               // 0..63
        int k = kc * 32 + (lane >> 4) * 8 + j;
        int ncol = nt * 16 + (lane & 15);
        float x = (ncol < C) ? Wl[(size_t)k * C + ncol] : 0.f;
        Wlh[idx] = (_Float16)x;
    }
}

__global__ void scan_block(const int* __restrict__ in, int* __restrict__ part,
                           int* __restrict__ bsums, int n) {
    __shared__ int tmp[256];
    int tid = threadIdx.x;
    int i = blockIdx.x * 256 + tid;
    int v = (i < n) ? in[i] : 0;
    tmp[tid] = v;
    __syncthreads();
    for (int o = 1; o < 256; o <<= 1) {
        int t = (tid >= o) ? tmp[tid - o] : 0;
        __syncthreads();
        tmp[tid] += t;
        __syncthreads();
    }
    if (i < n) part[i] = tmp[tid] - v;
    if (tid == 255) bsums[blockIdx.x] = tmp[255];
}

__global__ void scan_finish(const int* __restrict__ part, const int* __restrict__ bsums,
                            int* __restrict__ offs, int n, int Etot) {
    __shared__ int acc[256];
    int b = blockIdx.x, tid = threadIdx.x;
    int s = 0;
    for (int i = tid; i < b; i += 256) s += bsums[i];
    acc[tid] = s;
    __syncthreads();
    for (int o = 128; o > 0; o >>= 1) {
        if (tid < o) acc[tid] += acc[tid + o];
        __syncthreads();
    }
    int prefix = acc[0];
    int i = b * 256 + tid;
    if (i < n) offs[i] = part[i] + prefix;
    if (b == 0 && tid == 0) offs[n] = Etot;
}

// ---------------- device bodies for the merged scatter||gemm dispatch --------------
__device__ __forceinline__ void dev_scatter(int bid,
                                            const int* __restrict__ src,
                                            const int* __restrict__ dst,
                                            const int* __restrict__ rank,
                                            const int* __restrict__ offs,
                                            int* __restrict__ csr_src, int E) {
    int e0 = (bid * 256 + threadIdx.x) * 8;
    if (e0 + 7 < E) {
        int4 d0 = *(const int4*)(dst + e0);
        int4 d1 = *(const int4*)(dst + e0 + 4);
        int4 s0 = *(const int4*)(src + e0);
        int4 s1 = *(const int4*)(src + e0 + 4);
        int4 r0 = *(const int4*)(rank + e0);
        int4 r1 = *(const int4*)(rank + e0 + 4);
        csr_src[offs[d0.x] + r0.x] = s0.x;
        csr_src[offs[d0.y] + r0.y] = s0.y;
        csr_src[offs[d0.z] + r0.z] = s0.z;
        csr_src[offs[d0.w] + r0.w] = s0.w;
        csr_src[offs[d1.x] + r1.x] = s1.x;
        csr_src[offs[d1.y] + r1.y] = s1.y;
        csr_src[offs[d1.z] + r1.z] = s1.z;
        csr_src[offs[d1.w] + r1.w] = s1.w;
    } else {
        for (int e = e0; e < E; ++e) {
            csr_src[offs[dst[e]] + rank[e]] = src[e];
        }
    }
}

__device__ __forceinline__ void dev_gemm_f32(int bid, char* lds,
                                             const float* __restrict__ X,
                                             const _Float16* __restrict__ Bh,
                                             const float* __restrict__ a_s,
                                             const float* __restrict__ a_d,
                                             _Float16* __restrict__ Hout,
                                             float* __restrict__ as_,
                                             float* __restrict__ ad_, int n) {
    _Float16* Xh = (_Float16*)lds;
    float* Hs = (float*)lds;

    int tid = threadIdx.x;
    int base = bid * GR;
    const float4* X4 = (const float4*)X;

#pragma unroll
    for (int i = 0; i < 4; ++i) {
        int idx = i * 256 + tid;
        int row = idx >> 5, c4 = idx & 31;
        int rs = base + row; if (rs >= n) rs = n - 1;
        float4 v = X4[(size_t)rs * 32 + c4];
        half4 hv = {(_Float16)v.x, (_Float16)v.y, (_Float16)v.z, (_Float16)v.w};
        *(half4*)(Xh + row * 136 + c4 * 4) = hv;
    }
    __syncthreads();

    int wid = tid >> 6, lane = tid & 63;
    int quad = lane >> 4, l16 = lane & 15;
    int rowA = (wid & 1) * 16 + l16;
    int ntb = (wid >> 1) * 4;

    f32x4 acc[4];
#pragma unroll
    for (int t = 0; t < 4; ++t) acc[t] = (f32x4){0.f, 0.f, 0.f, 0.f};

    for (int kc = 0; kc < 4; ++kc) {
        half8 Ah = *(const half8*)(Xh + rowA * 136 + kc * 32 + quad * 8);
#pragma unroll
        for (int nt = 0; nt < 4; ++nt) {
            half8 Bv = *(const half8*)(Bh + (((size_t)((ntb + nt) * 4 + kc)) * 64 + lane) * 8);
            acc[nt] = __builtin_amdgcn_mfma_f32_16x16x32_f16(Ah, Bv, acc[nt], 0, 0, 0);
        }
    }
    __syncthreads();

    int rowD0 = (wid & 1) * 16 + quad * 4;
#pragma unroll
    for (int nt = 0; nt < 4; ++nt)
#pragma unroll
        for (int r = 0; r < 4; ++r)
            Hs[(rowD0 + r) * 136 + (ntb + nt) * 16 + l16] = acc[nt][r];
    __syncthreads();

    const float4* Hs4 = (const float4*)Hs;
    half4* H4 = (half4*)Hout;
#pragma unroll
    for (int i = 0; i < 4; ++i) {
        int idx = i * 256 + tid;
        int row = idx >> 5, c4 = idx & 31;
        int grow = base + row;
        if (grow < n) {
            float4 v = Hs4[row * 34 + c4];
            half4 hv = {(_Float16)v.x, (_Float16)v.y, (_Float16)v.z, (_Float16)v.w};
            H4[(size_t)grow * 32 + c4] = hv;
        }
    }

    // dots (fp32 from LDS): thread -> row tid>>3, eighth tid&7, reduce over 8 lanes
    int drow = tid >> 3, q = tid & 7;
    const float4* as4 = (const float4*)a_s;
    const float4* ad4 = (const float4*)a_d;
    float s = 0.f, d = 0.f;
#pragma unroll
    for (int j = 0; j < 4; ++j) {
        float4 v = Hs4[drow * 34 + q * 4 + j];
        float4 a = as4[q * 4 + j];
        float4 b = ad4[q * 4 + j];
        s += v.x * a.x + v.y * a.y + v.z * a.z + v.w * a.w;
        d += v.x * b.x + v.y * b.y + v.z * b.z + v.w * b.w;
    }
    s += __shfl_xor(s, 1, WAVE); s += __shfl_xor(s, 2, WAVE); s += __shfl_xor(s, 4, WAVE);
    d += __shfl_xor(d, 1, WAVE); d += __shfl_xor(d, 2, WAVE); d += __shfl_xor(d, 4, WAVE);
    if (q == 0 && base + drow < n) {
        as_[base + drow] = s;
        ad_[base + drow] = d;
    }
}

// merged dispatch — blocks [0,nbS): atomic-free scatter; [nbS,nbS+nbT): GEMM L1.
__global__ __launch_bounds__(256) void scatter_gemm(const int* __restrict__ src,
                                                    const int* __restrict__ dst,
                                                    const int* __restrict__ rank,
                                                    const int* __restrict__ offs,
                                                    int* __restrict__ csr_src, int E, int nbS,
                                                    const float* __restrict__ X,
                                                    const _Float16* __restrict__ Bh,
                                                    const float* __restrict__ a_s,
                                                    const float* __restrict__ a_d,
                                                    _Float16* __restrict__ Hout,
                                                    float* __restrict__ as_,
                                                    float* __restrict__ ad_, int n) {
    __shared__ char lds[GR * 136 * 4];
    if (blockIdx.x < nbS) {
        dev_scatter(blockIdx.x, src, dst, rank, offs, csr_src, E);
    } else {
        dev_gemm_f32(blockIdx.x - nbS, lds, X, Bh, a_s, a_d, Hout, as_, ad_, n);
    }
}

// ---------------- same GEMM with fp16 X input (layer-2) — staging is pure copy -----
__global__ __launch_bounds__(256) void gemm_mfma_h(const _Float16* __restrict__ X,
                                                   const _Float16* __restrict__ Bh,
                                                   const float* __restrict__ a_s,
                                                   const float* __restrict__ a_d,
                                                   _Float16* __restrict__ Hout,
                                                   float* __restrict__ as_,
                                                   float* __restrict__ ad_, int n) {
    __shared__ char lds[GR * 136 * 4];
    _Float16* Xh = (_Float16*)lds;
    float* Hs = (float*)lds;

    int tid = threadIdx.x;
    int base = blockIdx.x * GR;
    const half8* X8 = (const half8*)X;

#pragma unroll
    for (int i = 0; i < 2; ++i) {
        int idx = i * 256 + tid;            // 0..511: 32 rows x 16 half8
        int row = idx >> 4, c8 = idx & 15;
        int rs = base + row; if (rs >= n) rs = n - 1;
        *(half8*)(Xh + row * 136 + c8 * 8) = X8[(size_t)rs * 16 + c8];
    }
    __syncthreads();

    int wid = tid >> 6, lane = tid & 63;
    int quad = lane >> 4, l16 = lane & 15;
    int rowA = (wid & 1) * 16 + l16;
    int ntb = (wid >> 1) * 4;

    f32x4 acc[4];
#pragma unroll
    for (int t = 0; t < 4; ++t) acc[t] = (f32x4){0.f, 0.f, 0.f, 0.f};

    for (int kc = 0; kc < 4; ++kc) {
        half8 Ah = *(const half8*)(Xh + rowA * 136 + kc * 32 + quad * 8);
#pragma unroll
        for (int nt = 0; nt < 4; ++nt) {
            half8 Bv = *(const half8*)(Bh + (((size_t)((ntb + nt) * 4 + kc)) * 64 + lane) * 8);
            acc[nt] = __builtin_amdgcn_mfma_f32_16x16x32_f16(Ah, Bv, acc[nt], 0, 0, 0);
        }
    }
    __syncthreads();

    int rowD0 = (wid & 1) * 16 + quad * 4;
#pragma unroll
    for (int nt = 0; nt < 4; ++nt)
#pragma unroll
        for (int r = 0; r < 4; ++r)
            Hs[(rowD0 + r) * 136 + (ntb + nt) * 16 + l16] = acc[nt][r];
    __syncthreads();

    const float4* Hs4 = (const float4*)Hs;
    half4* H4 = (half4*)Hout;
#pragma unroll
    for (int i = 0; i < 4; ++i) {
        int idx = i * 256 + tid;
        int row = idx >> 5, c4 = idx & 31;
        int grow = base + row;
        if (grow < n) {
            float4 v = Hs4[row * 34 + c4];
            half4 hv = {(_Float16)v.x, (_Float16)v.y, (_Float16)v.z, (_Float16)v.w};
            H4[(size_t)grow * 32 + c4] = hv;
        }
    }

    int drow = tid >> 3, q = tid & 7;
    const float4* as4 = (const float4*)a_s;
    const float4* ad4 = (const float4*)a_d;
    float s = 0.f, d = 0.f;
#pragma unroll
    for (int j = 0; j < 4; ++j) {
        float4 v = Hs4[drow * 34 + q * 4 + j];
        float4 a = as4[q * 4 + j];
        float4 b = ad4[q * 4 + j];
        s += v.x * a.x + v.y * a.y + v.z * a.z + v.w * a.w;
        d += v.x * b.x + v.y * b.y + v.z * b.z + v.w * b.w;
    }
    s += __shfl_xor(s, 1, WAVE); s += __shfl_xor(s, 2, WAVE); s += __shfl_xor(s, 4, WAVE);
    d += __shfl_xor(d, 1, WAVE); d += __shfl_xor(d, 2, WAVE); d += __shfl_xor(d, 4, WAVE);
    if (q == 0 && base + drow < n) {
        as_[base + drow] = s;
        ad_[base + drow] = d;
    }
}

__device__ __forceinline__ float leaky02(float x) { return x > 0.f ? x : 0.2f * x; }

// ---------------- GAT aggregation: fused edge weights, 8 edges/iter, dual acc -----------
__global__ __launch_bounds__(256) void gat_aggregate(const _Float16* __restrict__ h,
                                                     const int* __restrict__ csr_src,
                                                     const float* __restrict__ as_,
                                                     const float* __restrict__ ad_,
                                                     const int* __restrict__ offs,
                                                     const float* __restrict__ bias,
                                                     _Float16* __restrict__ out, int n, int act) {
    int node = blockIdx.x * 4 + (threadIdx.x >> 6);
    int lane = threadIdx.x & 63;
    if (node >= n) return;
    int beg = offs[node], end = offs[node + 1];
    int q4 = lane >> 4, l = lane & 15;
    const half8* h8 = (const half8*)h;

    float adn = ad_[node];
    float w_self = __expf(leaky02(as_[node] + adn));
    float facc[8], facc2[8];
    {
        half8 v = h8[(size_t)node * 16 + l];
        float ws = (q4 == 0) ? w_self : 0.f;
#pragma unroll
        for (int i = 0; i < 8; ++i) { facc[i] = ws * (float)v[i]; facc2[i] = 0.f; }
    }
    float sacc = (lane == 0) ? w_self : 0.f;
    for (int j = beg; j < end; j += 8) {
        int j0 = j + q4;
        int j1 = j0 + 4;
        bool vA = j0 < end;
        bool vB = j1 < end;
        int jA = vA ? j0 : (end - 1);
        int jB = vB ? j1 : (end - 1);
        int sA = csr_src[jA];
        int sB = csr_src[jB];
        half8 a = h8[(size_t)sA * 16 + l];
        half8 b = h8[(size_t)sB * 16 + l];
        float asA = as_[sA];
        float asB = as_[sB];
        float wA = vA ? __expf(leaky02(asA + adn)) : 0.f;
        float wB = vB ? __expf(leaky02(asB + adn)) : 0.f;
#pragma unroll
        for (int i = 0; i < 8; ++i) {
            facc[i]  = fmaf(wA, (float)a[i], facc[i]);
            facc2[i] = fmaf(wB, (float)b[i], facc2[i]);
        }
        sacc += (l == 0) ? (wA + wB) : 0.f;
    }
#pragma unroll
    for (int i = 0; i < 8; ++i) {
        facc[i] += facc2[i];
        facc[i] += __shfl_xor(facc[i], 16, WAVE);
        facc[i] += __shfl_xor(facc[i], 32, WAVE);
    }
    sacc += __shfl_xor(sacc, 16, WAVE);
    sacc += __shfl_xor(sacc, 32, WAVE);
    float inv_s = 1.f / __shfl(sacc, 0, WAVE);
    if (q4 == 0) {
        const float4* b4 = (const float4*)bias;
        float4 b0 = b4[l * 2], b1 = b4[l * 2 + 1];
        float o[8];
        o[0] = fmaf(facc[0], inv_s, b0.x);
        o[1] = fmaf(facc[1], inv_s, b0.y);
        o[2] = fmaf(facc[2], inv_s, b0.z);
        o[3] = fmaf(facc[3], inv_s, b0.w);
        o[4] = fmaf(facc[4], inv_s, b1.x);
        o[5] = fmaf(facc[5], inv_s, b1.y);
        o[6] = fmaf(facc[6], inv_s, b1.z);
        o[7] = fmaf(facc[7], inv_s, b1.w);
        if (act == 1) {
#pragma unroll
            for (int i = 0; i < 8; ++i) o[i] = o[i] > 0.f ? o[i] : expm1f(o[i]);
        }
        half8 hv;
#pragma unroll
        for (int i = 0; i < 8; ++i) hv[i] = (_Float16)o[i];
        ((half8*)(out + (size_t)node * 128))[l] = hv;
    }
}

// ---------------- energy via fp16 MFMA; GR2=64 rows, all 4 waves active ------------
__global__ __launch_bounds__(256) void energy_mfma(const _Float16* __restrict__ X,
                                                   const _Float16* __restrict__ Ph,
                                                   const float* __restrict__ bp1,
                                                   const float* __restrict__ Wp2,
                                                   const float* __restrict__ bp2,
                                                   float* __restrict__ energy, int n, int HP) {
    __shared__ _Float16 Xh[GR2 * 136];   // 17408 B
    int tid = threadIdx.x;
    int base = blockIdx.x * GR2;
    const half8* X8 = (const half8*)X;
#pragma unroll
    for (int i = 0; i < 4; ++i) {
        int idx = i * 256 + tid;            // 64 rows x 16 half8
        int row = idx >> 4, c8 = idx & 15;
        int rs = base + row; if (rs >= n) rs = n - 1;
        *(half8*)(Xh + row * 136 + c8 * 8) = X8[(size_t)rs * 16 + c8];
    }
    __syncthreads();

    int wid = tid >> 6, lane = tid & 63;
    int quad = lane >> 4, l16 = lane & 15;
    int rowA = wid * 16 + l16;

    f32x4 acc0 = (f32x4){0.f, 0.f, 0.f, 0.f};
    f32x4 acc1 = (f32x4){0.f, 0.f, 0.f, 0.f};
    for (int kc = 0; kc < 4; ++kc) {
        half8 Ah = *(const half8*)(Xh + rowA * 136 + kc * 32 + quad * 8);
        half8 B0 = *(const half8*)(Ph + (((size_t)kc) * 64 + lane) * 8);
        half8 B1 = *(const half8*)(Ph + (((size_t)(4 + kc)) * 64 + lane) * 8);
        acc0 = __builtin_amdgcn_mfma_f32_16x16x32_f16(Ah, B0, acc0, 0, 0, 0);
        acc1 = __builtin_amdgcn_mfma_f32_16x16x32_f16(Ah, B1, acc1, 0, 0, 0);
    }

    float b0 = bp1[l16];
    float w0 = Wp2[l16];
    int c1 = 16 + l16;
    int c1c = c1 < HP ? c1 : HP - 1;
    float b1 = bp1[c1c];
    float w1 = (c1 < HP) ? Wp2[c1c] : 0.f;
    float bp2v = bp2[0];
#pragma unroll
    for (int r = 0; r < 4; ++r) {
        float h0 = acc0[r] + b0;
        h0 = h0 > 0.f ? h0 : 0.f;
        float h1 = acc1[r] + b1;
        h1 = h1 > 0.f ? h1 : 0.f;
        float v = h0 * w0 + h1 * w1;
        v += __shfl_xor(v, 1, WAVE);
        v += __shfl_xor(v, 2, WAVE);
        v += __shfl_xor(v, 4, WAVE);
        v += __shfl_xor(v, 8, WAVE);
        int row = base + wid * 16 + quad * 4 + r;
        if (l16 == 0 && row < n) energy[row] = v + bp2v;
    }
}

// ---------------- segment softmax-pool, 2 blocks/segment (64 cols each), fp16 X ----
__global__ __launch_bounds__(256) void seg_pool(const _Float16* __restrict__ X,
                                                const float* __restrict__ energy,
                                                const int* __restrict__ node_pos,
                                                float* __restrict__ pooled) {
    int g = blockIdx.x >> 1;
    int bn = blockIdx.x & 1;          // which 64-col half
    int beg = node_pos[g], end = node_pos[g + 1];
    int tid = threadIdx.x;
    int wid = tid >> 6, lane = tid & 63;
    __shared__ float swr[8];
    __shared__ float4 red[256];

    float m = -INFINITY;
    for (int i = beg + tid; i < end; i += 256) m = fmaxf(m, energy[i]);
#pragma unroll
    for (int o = 1; o < 64; o <<= 1) m = fmaxf(m, __shfl_xor(m, o, WAVE));
    if (lane == 0) swr[wid] = m;
    __syncthreads();
    m = fmaxf(fmaxf(swr[0], swr[1]), fmaxf(swr[2], swr[3]));

    float s = 0.f;
    for (int i = beg + tid; i < end; i += 256) s += __expf(energy[i] - m);
#pragma unroll
    for (int o = 1; o < 64; o <<= 1) s += __shfl_xor(s, o, WAVE);
    if (lane == 0) swr[4 + wid] = s;
    __syncthreads();
    s = swr[4] + swr[5] + swr[6] + swr[7];
    float inv = (end > beg && s > 0.f) ? 1.f / s : 0.f;

    int cq = tid & 15;       // 4 cols each -> 64 cols per block
    int rg = tid >> 4;       // 16 row-groups
    const half4* X4 = (const half4*)X;   // 32 half4 per row
    float4 acc = make_float4(0.f, 0.f, 0.f, 0.f);
#pragma unroll 2
    for (int i = beg + rg; i < end; i += 16) {
        float w = __expf(energy[i] - m) * inv;
        half4 v = X4[(size_t)i * 32 + bn * 16 + cq];
        acc.x = fmaf(w, (float)v.x, acc.x);
        acc.y = fmaf(w, (float)v.y, acc.y);
        acc.z = fmaf(w, (float)v.z, acc.z);
        acc.w = fmaf(w, (float)v.w, acc.w);
    }
    red[tid] = acc;
#pragma unroll
    for (int o = 8; o >= 1; o >>= 1) {
        __syncthreads();
        if (rg < o) {
            float4 t = red[tid + o * 16];
            acc.x += t.x; acc.y += t.y; acc.z += t.z; acc.w += t.w;
            red[tid] = acc;
        }
    }
    if (rg == 0)
        ((float4*)(pooled + (size_t)g * 128 + bn * 64))[cq] = acc;
}

// ---------------- classifier GEMM pooled[G x 128] @ Wl[128 x C] via fp16 MFMA ------
__global__ __launch_bounds__(256) void classify_mfma(const float* __restrict__ P,
                                                     const _Float16* __restrict__ Wlh,
                                                     const float* __restrict__ bl,
                                                     float* __restrict__ out,
                                                     int G_, int C, int nbM) {
    __shared__ _Float16 Xh[GR * 136];
    int tid = threadIdx.x;
    int bm = blockIdx.x % nbM;
    int bn = blockIdx.x / nbM;
    int base = bm * GR;
    const float4* X4 = (const float4*)P;
#pragma unroll
    for (int i = 0; i < 4; ++i) {
        int idx = i * 256 + tid;
        int row = idx >> 5, c4 = idx & 31;
        int rs = base + row; if (rs >= G_) rs = G_ - 1;
        float4 v = X4[(size_t)rs * 32 + c4];
        half4 hv = {(_Float16)v.x, (_Float16)v.y, (_Float16)v.z, (_Float16)v.w};
        *(half4*)(Xh + row * 136 + c4 * 4) = hv;
    }
    __syncthreads();

    int wid = tid >> 6, lane = tid & 63;
    int quad = lane >> 4, l16 = lane & 15;
    int rowA = (wid & 1) * 16 + l16;
    int ntb = bn * 8 + (wid >> 1) * 4;   // global 16-col tile index

    f32x4 acc[4];
#pragma unroll
    for (int t = 0; t < 4; ++t) acc[t] = (f32x4){0.f, 0.f, 0.f, 0.f};

    for (int kc = 0; kc < 4; ++kc) {
        half8 Ah = *(const half8*)(Xh + rowA * 136 + kc * 32 + quad * 8);
#pragma unroll
        for (int nt = 0; nt < 4; ++nt) {
            half8 Bv = *(const half8*)(Wlh + (((size_t)((ntb + nt) * 4 + kc)) * 64 + lane) * 8);
            acc[nt] = __builtin_amdgcn_mfma_f32_16x16x32_f16(Ah, Bv, acc[nt], 0, 0, 0);
        }
    }

    int row0 = base + (wid & 1) * 16 + quad * 4;
#pragma unroll
    for (int nt = 0; nt < 4; ++nt) {
        int col = (ntb + nt) * 16 + l16;
        if (col < C) {
            float b = bl[col];
#pragma unroll
            for (int r = 0; r < 4; ++r) {
                int row = row0 + r;
                if (row < G_) out[(size_t)row * C + col] = acc[nt][r] + b;
            }
        }
    }
}

extern "C" void kernel_launch(void* const* d_in, const int* in_sizes, int n_in,
                              void* d_out, int out_size, void* d_ws, size_t ws_size,
                              hipStream_t stream) {
    const float* cfg_nodes = (const float*)d_in[0];
    const int* rel = (const int*)d_in[1];
    const int* node_pos = (const int*)d_in[2];
    const float* W_g1 = (const float*)d_in[3];
    const float* att_src1 = (const float*)d_in[4];
    const float* att_dst1 = (const float*)d_in[5];
    const float* b_g1 = (const float*)d_in[6];
    const float* W_g2 = (const float*)d_in[7];
    const float* att_src2 = (const float*)d_in[8];
    const float* att_dst2 = (const float*)d_in[9];
    const float* b_g2 = (const float*)d_in[10];
    const float* Wp1 = (const float*)d_in[11];
    const float* bp1 = (const float*)d_in[12];
    const float* Wp2 = (const float*)d_in[13];
    const float* bp2 = (const float*)d_in[14];
    const float* Wl = (const float*)d_in[15];
    const float* bl = (const float*)d_in[16];

    const int N = in_sizes[0] / 128;
    const int E = in_sizes[1] / 2;
    const int G = in_sizes[2] - 1;
    const int HP = in_sizes[12];
    const int C = out_size / G;

    const int* srcArr = rel;
    const int* dstArr = rel + E;

    char* w = (char*)d_ws;
    auto carve = [&](size_t bytes) -> char* {
        char* p = w;
        w += (bytes + 255) & ~(size_t)255;
        return p;
    };
    _Float16* bufH = (_Float16*)carve((size_t)N * 128 * 2);   // gemm output (gat gather src)
    _Float16* bufF = (_Float16*)carve((size_t)N * 128 * 2);   // aggregate output (fp16)
    float* asv = (float*)carve((size_t)N * 4);
    float* adv = (float*)carve((size_t)N * 4);
    float* energy = (float*)carve((size_t)N * 4);
    int* deg = (int*)carve((size_t)N * 4);
    int* offs = (int*)carve((size_t)(N + 1) * 4);
    int* csr_src = (int*)carve((size_t)E * 4);
    int* rank = (int*)carve((size_t)E * 4);
    int* bsums = (int*)carve(1024);
    _Float16* W1h = (_Float16*)carve(16384 * 2);
    _Float16* W2h = (_Float16*)carve(16384 * 2);
    _Float16* Ph = (_Float16*)carve(4096 * 2);
    _Float16* Wlh = (_Float16*)carve(131072 * 2);
    float* pooled = (float*)carve((size_t)G * 128 * 4);

    const int nbN = (N + 255) / 256;
    const int nbC = ((E + 1) / 2 + 255) / 256;   // count: 2 edges/thread
    const int nbS = ((E + 7) / 8 + 255) / 256;   // scatter: 8 edges/thread
    const int nbT = (N + GR - 1) / GR;           // GEMM tiles (32 rows)
    const int nbT2 = (N + GR2 - 1) / GR2;        // energy tiles (64 rows)
    const int nbM = (G + GR - 1) / GR;           // classifier row tiles
    const int nbCt = (C + 127) / 128;            // classifier col slabs

    // ---- CSR build (rank-based) + all weight packs ----
    hipMemsetAsync(deg, 0, (size_t)N * 4, stream);
    count_pack<<<nbC + 656, 256, 0, stream>>>(dstArr, deg, rank, E, nbC,
                                              W_g1, W_g2, W1h, W2h, Wp1, HP, Ph,
                                              Wl, C, Wlh);
    scan_block<<<nbN, 256, 0, stream>>>(deg, offs, bsums, N);
    scan_finish<<<nbN, 256, 0, stream>>>(offs, bsums, offs, N, E);

    // ---- merged: atomic-free scatter || GAT layer-1 GEMM (independent work) ----
    scatter_gemm<<<nbS + nbT, 256, 0, stream>>>(srcArr, dstArr, rank, offs, csr_src, E, nbS,
                                                cfg_nodes, W1h, att_src1, att_dst1,
                                                bufH, asv, adv, N);

    // ---- GAT layer 1 aggregate ----
    gat_aggregate<<<(N + 3) / 4, 256, 0, stream>>>(bufH, csr_src, asv, adv, offs, b_g1, bufF, N, 1);

    // ---- GAT layer 2 (fp16 input) ----
    gemm_mfma_h<<<nbT, 256, 0, stream>>>(bufF, W2h, att_src2, att_dst2,
                                         bufH, asv, adv, N);
    gat_aggregate<<<(N + 3) / 4, 256, 0, stream>>>(bufH, csr_src, asv, adv, offs, b_g2, bufF, N, 0);

    // ---- energy (fp16 MFMA, GR2=64) + pooling + classifier ----
    energy_mfma<<<nbT2, 256, 0, stream>>>(bufF, Ph, bp1, Wp2, bp2, energy, N, HP);
    seg_pool<<<G * 2, 256, 0, stream>>>(bufF, energy, node_pos, pooled);
    classify_mfma<<<nbM * nbCt, 256, 0, stream>>>(pooled, Wlh, bl, (float*)d_out, G, C, nbM);
}